// Round 14
// baseline (307.628 us; speedup 1.0000x reference)
//
#include <hip/hip_runtime.h>
#include <math.h>

#define IN_F 128
#define F1 256   // H1*C1
#define H1 2
#define F2 64
#define NEG 0.2f

typedef _Float16 f16x8 __attribute__((ext_vector_type(8)));
typedef _Float16 f16x4 __attribute__((ext_vector_type(4)));
typedef float f32x4 __attribute__((ext_vector_type(4)));

// ------- fused layer-1 + layer-2 GEMM --------------------------------------
// Replaces gemm1_mfma + gemm2_mfma. Per block: 4 waves x 16 rows = 64 rows.
// z (post-ReLU, split f16 hi/lo) staged in LDS instead of HBM round-trip
// (saves ~100MB traffic + 1 launch boundary). Frag region (64KB) reused
// across 3 phases: W1-h0 -> W1-h1 -> W2. z store swizzled: elem ^= (row&7)<<3
// (keeps 16B alignment of gemm2's f16x8 reads; c0 is 8-elem aligned).
// All threads reach all barriers; compute guarded by `active`.
__global__ __launch_bounds__(256) void gemm12_fused(
    const _Float16* __restrict__ Gh, const _Float16* __restrict__ Gl,
    const _Float16* __restrict__ Wth, const _Float16* __restrict__ Wtl,
    const float* __restrict__ b1,
    const _Float16* __restrict__ W2th, const _Float16* __restrict__ W2tl,
    const float* __restrict__ as2, const float* __restrict__ ad2,
    float* __restrict__ xh2, float* __restrict__ a_src, float* __restrict__ a_dst,
    int N)
{
    __shared__ _Float16 FRGh[32 * 64 * 8];   // 32 KB
    __shared__ _Float16 FRGl[32 * 64 * 8];   // 32 KB
    __shared__ _Float16 Zh[64 * 256];        // 32 KB
    __shared__ _Float16 Zl[64 * 256];        // 32 KB

    int t = threadIdx.x;
    int wave = t >> 6, lane = t & 63;
    int quad = lane >> 4, l4 = lane & 15;
    int rt = blockIdx.x * 4 + wave;
    bool active = (rt * 16 < N);
    long mrow = (long)rt * 16 + l4;

    // ---- phases 1,2: layer-1 GEMM per head, z -> LDS ------------------------
    #pragma unroll 1
    for (int h = 0; h < 2; ++h) {
        // load W1-head-h fragments (32 slots: ct<8, ks<4)
        const _Float16* wsh = Wth + (long)h * 128 * IN_F;
        const _Float16* wsl = Wtl + (long)h * 128 * IN_F;
        #pragma unroll
        for (int p = 0; p < 8; ++p) {
            int fs = p * 256 + t;
            int fl = fs & 63;
            int slot = fs >> 6;
            int ct = slot >> 2, ks = slot & 3;
            int col = ct * 16 + (fl & 15);
            int koff = ks * 32 + (fl >> 4) * 8;
            *(f16x8*)&FRGh[fs * 8] = *(const f16x8*)&wsh[(long)col * IN_F + koff];
            *(f16x8*)&FRGl[fs * 8] = *(const f16x8*)&wsl[(long)col * IN_F + koff];
        }
        __syncthreads();

        if (active) {
            const _Float16* gh = Gh + mrow * F1 + h * 128 + quad * 8;
            const _Float16* gl = Gl + mrow * F1 + h * 128 + quad * 8;
            f16x8 ah[4], al[4];
            #pragma unroll
            for (int ks = 0; ks < 4; ++ks) {
                ah[ks] = *(const f16x8*)(gh + ks * 32);
                al[ks] = *(const f16x8*)(gl + ks * 32);
            }
            f32x4 acc[8];
            #pragma unroll
            for (int ct = 0; ct < 8; ++ct) acc[ct] = (f32x4){0.f, 0.f, 0.f, 0.f};
            #pragma unroll
            for (int ks = 0; ks < 4; ++ks) {
                #pragma unroll
                for (int ct = 0; ct < 8; ++ct) {
                    f16x8 bh = *(const f16x8*)&FRGh[((ct * 4 + ks) * 64 + lane) * 8];
                    f16x8 bl = *(const f16x8*)&FRGl[((ct * 4 + ks) * 64 + lane) * 8];
                    acc[ct] = __builtin_amdgcn_mfma_f32_16x16x32_f16(ah[ks], bh, acc[ct], 0, 0, 0);
                    acc[ct] = __builtin_amdgcn_mfma_f32_16x16x32_f16(al[ks], bh, acc[ct], 0, 0, 0);
                    acc[ct] = __builtin_amdgcn_mfma_f32_16x16x32_f16(ah[ks], bl, acc[ct], 0, 0, 0);
                }
            }
            // epilogue: relu(acc+b1) -> split f16 -> LDS z (swizzled)
            #pragma unroll
            for (int ct = 0; ct < 8; ++ct) {
                int col = h * 128 + ct * 16 + l4;
                float b1c = b1[col];
                #pragma unroll
                for (int i = 0; i < 4; ++i) {
                    int row = wave * 16 + quad * 4 + i;
                    float v = fmaxf(acc[ct][i] + b1c, 0.f);
                    _Float16 hi = (_Float16)v;
                    int e = (row * 256 + col) ^ ((row & 7) << 3);
                    Zh[e] = hi;
                    Zl[e] = (_Float16)(v - (float)hi);
                }
            }
        }
        __syncthreads();
    }

    // ---- phase 3: layer-2 GEMM from LDS z + att2 epilogue -------------------
    // load W2 fragments (32 slots: ct<4, ks<8)
    #pragma unroll
    for (int p = 0; p < 8; ++p) {
        int fs = p * 256 + t;
        int fl = fs & 63;
        int slot = fs >> 6;
        int ct = slot >> 3, ks = slot & 7;
        int col = ct * 16 + (fl & 15);
        int koff = ks * 32 + (fl >> 4) * 8;
        *(f16x8*)&FRGh[fs * 8] = *(const f16x8*)&W2th[(long)col * F1 + koff];
        *(f16x8*)&FRGl[fs * 8] = *(const f16x8*)&W2tl[(long)col * F1 + koff];
    }
    __syncthreads();

    if (!active) return;
    {
        int row = wave * 16 + l4;
        int swz = (row & 7) << 3;
        f16x8 ah[8], al[8];
        #pragma unroll
        for (int ks = 0; ks < 8; ++ks) {
            int e = (row * 256 + (quad * 8 + ks * 32)) ^ swz;
            ah[ks] = *(const f16x8*)&Zh[e];
            al[ks] = *(const f16x8*)&Zl[e];
        }
        f32x4 acc[4];
        #pragma unroll
        for (int ct = 0; ct < 4; ++ct) acc[ct] = (f32x4){0.f, 0.f, 0.f, 0.f};
        #pragma unroll
        for (int ks = 0; ks < 8; ++ks) {
            #pragma unroll
            for (int ct = 0; ct < 4; ++ct) {
                f16x8 bh = *(const f16x8*)&FRGh[((ct * 8 + ks) * 64 + lane) * 8];
                f16x8 bl = *(const f16x8*)&FRGl[((ct * 8 + ks) * 64 + lane) * 8];
                acc[ct] = __builtin_amdgcn_mfma_f32_16x16x32_f16(ah[ks], bh, acc[ct], 0, 0, 0);
                acc[ct] = __builtin_amdgcn_mfma_f32_16x16x32_f16(al[ks], bh, acc[ct], 0, 0, 0);
                acc[ct] = __builtin_amdgcn_mfma_f32_16x16x32_f16(ah[ks], bl, acc[ct], 0, 0, 0);
            }
        }
        int rbase = rt * 16 + quad * 4;
        float ps[4] = {0, 0, 0, 0}, pd[4] = {0, 0, 0, 0};
        #pragma unroll
        for (int ct = 0; ct < 4; ++ct) {
            int col = ct * 16 + l4;
            float asv = as2[col], adv = ad2[col];
            #pragma unroll
            for (int i = 0; i < 4; ++i) {
                xh2[(long)(rbase + i) * F2 + col] = acc[ct][i];
                ps[i] = fmaf(acc[ct][i], asv, ps[i]);
                pd[i] = fmaf(acc[ct][i], adv, pd[i]);
            }
        }
        #pragma unroll
        for (int o = 1; o < 16; o <<= 1) {
            #pragma unroll
            for (int i = 0; i < 4; ++i) {
                ps[i] += __shfl_xor(ps[i], o);
                pd[i] += __shfl_xor(pd[i], o);
            }
        }
        if (l4 == 0) {
            #pragma unroll
            for (int i = 0; i < 4; ++i) {
                a_src[rbase + i] = ps[i];
                a_dst[rbase + i] = pd[i];
            }
        }
    }
}

// ------- launch 1: histogram + PARALLEL UV/W1/W2 prep ------------------------
__global__ __launch_bounds__(256) void hist_uv_k(
    const int* __restrict__ ei_d, int* __restrict__ deg, int* __restrict__ pos,
    int E, int Ep, int NBH,
    const float* __restrict__ W1, const float* __restrict__ as1,
    const float* __restrict__ ad1, float* __restrict__ UV4,
    _Float16* __restrict__ Wth, _Float16* __restrict__ Wtl,
    const float* __restrict__ W2,
    _Float16* __restrict__ W2th, _Float16* __restrict__ W2tl)
{
    int b = (int)blockIdx.x;
    int t = threadIdx.x;
    if (b < NBH) {
        int i = b * 256 + t;
        if (i >= Ep) return;
        int d = (i < E) ? ei_d[i] : (i - E);
        pos[i] = atomicAdd(&deg[d], 1);
    } else if (b < NBH + 16) {
        // UV: pair p=(k,h), 16 lanes each, lane covers 8 contiguous c
        int p = (b - NBH) * 16 + (t >> 4);   // 0..255
        int l = t & 15;
        int k = p >> 1, h = p & 1;
        const float* wrow = W1 + (long)k * F1 + h * 128;
        const float* sa = as1 + h * 128;
        const float* da = ad1 + h * 128;
        int c0 = l * 8;
        float u = 0.f, v = 0.f;
        #pragma unroll
        for (int c = 0; c < 8; ++c) {
            float w = wrow[c0 + c];
            u = fmaf(w, sa[c0 + c], u);
            v = fmaf(w, da[c0 + c], v);
        }
        #pragma unroll
        for (int o = 1; o < 16; o <<= 1) {
            u += __shfl_xor(u, o);
            v += __shfl_xor(v, o);
        }
        if (l == 0) {
            UV4[k * 4 + h] = u;
            UV4[k * 4 + 2 + h] = v;
        }
    } else if (b < NBH + 32) {
        // W1 split-transpose: gid in [0,4096), n=gid/16, kb=(gid%16)*8
        int gid = (b - NBH - 16) * 256 + t;
        int n = gid >> 4;
        int kb = (gid & 15) * 8;
        f16x8 hi, lo;
        #pragma unroll
        for (int c = 0; c < 8; ++c) {
            float w = W1[(long)(kb + c) * F1 + n];
            _Float16 hh = (_Float16)w;
            hi[c] = hh;
            lo[c] = (_Float16)(w - (float)hh);
        }
        *(f16x8*)&Wth[(long)n * IN_F + kb] = hi;
        *(f16x8*)&Wtl[(long)n * IN_F + kb] = lo;
    } else {
        // W2 split-transpose: gid in [0,2048), n=gid/32, kb=(gid%32)*8
        int gid = (b - NBH - 32) * 256 + t;
        int n = gid >> 5;
        int kb = (gid & 31) * 8;
        f16x8 hi, lo;
        #pragma unroll
        for (int c = 0; c < 8; ++c) {
            float w = W2[(long)(kb + c) * F2 + n];
            _Float16 hh = (_Float16)w;
            hi[c] = hh;
            lo[c] = (_Float16)(w - (float)hh);
        }
        *(f16x8*)&W2th[(long)n * F1 + kb] = hi;
        *(f16x8*)&W2tl[(long)n * F1 + kb] = lo;
    }
}

// ------- launch 2: per-block local scan -> rloc + att1v ----------------------
__global__ __launch_bounds__(1024) void scanA_att_k(
    const int* __restrict__ deg, int* __restrict__ rloc, int* __restrict__ bsum,
    int N, int NBLK,
    const float* __restrict__ x, const float* __restrict__ UV4,
    float* __restrict__ a_src, float* __restrict__ a_dst)
{
    if ((int)blockIdx.x < NBLK) {
        __shared__ int wsum[16];
        int t = threadIdx.x, lane = t & 63, w = t >> 6;
        int i = blockIdx.x * 1024 + t;
        int v = (i < N) ? deg[i] : 0;
        int incl = v;
        #pragma unroll
        for (int o = 1; o < 64; o <<= 1) {
            int nb = __shfl_up(incl, o);
            if (lane >= o) incl += nb;
        }
        if (lane == 63) wsum[w] = incl;
        __syncthreads();
        if (w == 0 && lane < 16) {
            int s = wsum[lane];
            #pragma unroll
            for (int o = 1; o < 16; o <<= 1) {
                int nb = __shfl_up(s, o);
                if (lane >= o) s += nb;
            }
            wsum[lane] = s;
        }
        __syncthreads();
        int woff = (w == 0) ? 0 : wsum[w - 1];
        if (i < N) rloc[i] = woff + incl - v;
        if (t == 1023) bsum[blockIdx.x] = woff + incl;
    } else {
        int wave = threadIdx.x >> 6, lane = threadIdx.x & 63;
        int n = ((int)blockIdx.x - NBLK) * 16 + wave;
        if (n >= N) return;
        float2 xv = ((const float2*)(x + (long)n * IN_F))[lane];
        float4 u0 = ((const float4*)UV4)[2 * lane];
        float4 u1 = ((const float4*)UV4)[2 * lane + 1];
        float p0 = xv.x * u0.x + xv.y * u1.x;
        float p1 = xv.x * u0.y + xv.y * u1.y;
        float p2 = xv.x * u0.z + xv.y * u1.z;
        float p3 = xv.x * u0.w + xv.y * u1.w;
        #pragma unroll
        for (int o = 32; o > 0; o >>= 1) {
            p0 += __shfl_xor(p0, o); p1 += __shfl_xor(p1, o);
            p2 += __shfl_xor(p2, o); p3 += __shfl_xor(p3, o);
        }
        if (lane == 0) {
            a_src[(long)n * 2 + 0] = p0; a_src[(long)n * 2 + 1] = p1;
            a_dst[(long)n * 2 + 0] = p2; a_dst[(long)n * 2 + 1] = p3;
        }
    }
}

// ------- launch 3 (fused): rowptr fixup + atomic-free scatter ----------------
__global__ __launch_bounds__(1024) void scat_fix_k(
    const int* __restrict__ ei_s, const int* __restrict__ ei_d,
    const int* __restrict__ rloc, const int* __restrict__ bsum,
    const int* __restrict__ pos, int* __restrict__ rowptr,
    int* __restrict__ csr_src, int* __restrict__ csr_eid,
    int E, int Ep, int N, int NBLK)
{
    __shared__ int bexs[64];
    __shared__ int tot_sh;
    int t = threadIdx.x;
    if (t < 64) {
        int v = (t < NBLK) ? bsum[t] : 0;
        int incl = v;
        #pragma unroll
        for (int o = 1; o < 64; o <<= 1) {
            int nb = __shfl_up(incl, o);
            if (t >= o) incl += nb;
        }
        bexs[t] = incl - v;
        if (t == NBLK - 1) tot_sh = incl;
    }
    __syncthreads();
    if ((int)blockIdx.x < NBLK) {
        int i = blockIdx.x * 1024 + t;
        if (i < N) rowptr[i] = rloc[i] + bexs[blockIdx.x];
        if ((int)blockIdx.x == NBLK - 1 && t == 0) rowptr[N] = tot_sh;
    } else {
        int i = ((int)blockIdx.x - NBLK) * 1024 + t;
        if (i >= Ep) return;
        int s = (i < E) ? ei_s[i] : (i - E);
        int d = (i < E) ? ei_d[i] : (i - E);
        int at = rloc[d] + bexs[d >> 10] + pos[i];
        csr_src[at] = s;
        csr_eid[at] = (i < E) ? i : -1;
    }
}

// ------- layer-1 aggregation: 16-lane groups, 2x-unrolled gather -------------
__global__ __launch_bounds__(256) void agg1x(
    const int* __restrict__ rowptr, const int* __restrict__ csr_src,
    const float* __restrict__ a_s, const float* __restrict__ a_d,  // [N,2]
    const float* __restrict__ x, _Float16* __restrict__ Gh,
    _Float16* __restrict__ Gl, int N)
{
    int wave = threadIdx.x >> 6, lane = threadIdx.x & 63;
    int d = blockIdx.x * 4 + wave;
    if (d >= N) return;
    int row = rowptr[d], end = rowptr[d + 1];
    int h = lane >> 5, l5 = lane & 31;
    int g = lane >> 4, q = lane & 15;
    float adh = a_d[(long)d * 2 + h];
    // acc[seg][head][4]: seg0=ch q*4, seg1=ch 64+q*4
    float acc[2][2][4];
    #pragma unroll
    for (int s0 = 0; s0 < 2; ++s0)
        #pragma unroll
        for (int h0 = 0; h0 < 2; ++h0)
            #pragma unroll
            for (int p = 0; p < 4; ++p) acc[s0][h0][p] = 0.f;
    float den = 0.f;
    for (int base = row; base < end; base += 32) {
        int cnt = min(32, end - base);
        int sreg = 0; float e = 0.f;
        if (l5 < cnt) {
            sreg = csr_src[base + l5];
            float v = a_s[(long)sreg * 2 + h] + adh;
            v = (v > 0.f) ? v : NEG * v;
            e = expf(v);
            den += e;
        }
        int jmax = (cnt + 3) >> 2;
        for (int j = 0; j < jmax; j += 2) {
            int mA = 4 * j + g;                 // mA <= 27
            int mB = mA + 4;                    // mB <= 31 (jmax <= 8)
            int sA = __shfl(sreg, mA);
            int sB = __shfl(sreg, mB);
            float w0A = __shfl(e, mA);
            float w1A = __shfl(e, 32 | mA);
            float w0B = __shfl(e, mB);
            float w1B = __shfl(e, 32 | mB);
            const float* xpA = x + (long)sA * IN_F + q * 4;
            const float* xpB = x + (long)sB * IN_F + q * 4;
            float4 a0 = *(const float4*)(xpA);
            float4 a1 = *(const float4*)(xpA + 64);
            float4 b0 = *(const float4*)(xpB);
            float4 b1 = *(const float4*)(xpB + 64);
            acc[0][0][0] = fmaf(w0A, a0.x, acc[0][0][0]);
            acc[0][0][1] = fmaf(w0A, a0.y, acc[0][0][1]);
            acc[0][0][2] = fmaf(w0A, a0.z, acc[0][0][2]);
            acc[0][0][3] = fmaf(w0A, a0.w, acc[0][0][3]);
            acc[1][0][0] = fmaf(w0A, a1.x, acc[1][0][0]);
            acc[1][0][1] = fmaf(w0A, a1.y, acc[1][0][1]);
            acc[1][0][2] = fmaf(w0A, a1.z, acc[1][0][2]);
            acc[1][0][3] = fmaf(w0A, a1.w, acc[1][0][3]);
            acc[0][1][0] = fmaf(w1A, a0.x, acc[0][1][0]);
            acc[0][1][1] = fmaf(w1A, a0.y, acc[0][1][1]);
            acc[0][1][2] = fmaf(w1A, a0.z, acc[0][1][2]);
            acc[0][1][3] = fmaf(w1A, a0.w, acc[0][1][3]);
            acc[1][1][0] = fmaf(w1A, a1.x, acc[1][1][0]);
            acc[1][1][1] = fmaf(w1A, a1.y, acc[1][1][1]);
            acc[1][1][2] = fmaf(w1A, a1.z, acc[1][1][2]);
            acc[1][1][3] = fmaf(w1A, a1.w, acc[1][1][3]);
            acc[0][0][0] = fmaf(w0B, b0.x, acc[0][0][0]);
            acc[0][0][1] = fmaf(w0B, b0.y, acc[0][0][1]);
            acc[0][0][2] = fmaf(w0B, b0.z, acc[0][0][2]);
            acc[0][0][3] = fmaf(w0B, b0.w, acc[0][0][3]);
            acc[1][0][0] = fmaf(w0B, b1.x, acc[1][0][0]);
            acc[1][0][1] = fmaf(w0B, b1.y, acc[1][0][1]);
            acc[1][0][2] = fmaf(w0B, b1.z, acc[1][0][2]);
            acc[1][0][3] = fmaf(w0B, b1.w, acc[1][0][3]);
            acc[0][1][0] = fmaf(w1B, b0.x, acc[0][1][0]);
            acc[0][1][1] = fmaf(w1B, b0.y, acc[0][1][1]);
            acc[0][1][2] = fmaf(w1B, b0.z, acc[0][1][2]);
            acc[0][1][3] = fmaf(w1B, b0.w, acc[0][1][3]);
            acc[1][1][0] = fmaf(w1B, b1.x, acc[1][1][0]);
            acc[1][1][1] = fmaf(w1B, b1.y, acc[1][1][1]);
            acc[1][1][2] = fmaf(w1B, b1.z, acc[1][1][2]);
            acc[1][1][3] = fmaf(w1B, b1.w, acc[1][1][3]);
        }
    }
    // den: reduce within each 32-lane half, then exchange across halves
    #pragma unroll
    for (int o = 16; o > 0; o >>= 1) den += __shfl_xor(den, o);
    float den_o = __shfl_xor(den, 32);
    float den0 = (h == 0) ? den : den_o;
    float den1 = (h == 0) ? den_o : den;
    // cross-group combine
    #pragma unroll
    for (int s0 = 0; s0 < 2; ++s0)
        #pragma unroll
        for (int h0 = 0; h0 < 2; ++h0)
            #pragma unroll
            for (int p = 0; p < 4; ++p) {
                float v = acc[s0][h0][p];
                v += __shfl_xor(v, 16);
                v += __shfl_xor(v, 32);
                acc[s0][h0][p] = v;
            }
    if (g == 0) {
        float inv0 = 1.0f / (den0 + 1e-16f);
        float inv1 = 1.0f / (den1 + 1e-16f);
        #pragma unroll
        for (int h0 = 0; h0 < 2; ++h0) {
            float inv = (h0 == 0) ? inv0 : inv1;
            #pragma unroll
            for (int s0 = 0; s0 < 2; ++s0) {
                f16x4 hi, lo;
                #pragma unroll
                for (int p = 0; p < 4; ++p) {
                    float v = acc[s0][h0][p] * inv;
                    hi[p] = (_Float16)v;
                    lo[p] = (_Float16)(v - (float)hi[p]);
                }
                long base = (long)d * F1 + h0 * 128 + s0 * 64 + q * 4;
                *(f16x4*)(Gh + base) = hi;
                *(f16x4*)(Gl + base) = lo;
            }
        }
    }
}

// ------- layer-2 aggregation: 8-lane groups, 2x-unrolled gather --------------
__global__ __launch_bounds__(256) void agg2_csr(
    const int* __restrict__ rowptr, const int* __restrict__ csr_src,
    const float* __restrict__ a_s, const float* __restrict__ a_d,  // [N]
    const float* __restrict__ xh2, const float* __restrict__ b2,
    float* __restrict__ out2b, int N)
{
    int wave = threadIdx.x >> 6, lane = threadIdx.x & 63;
    int d = blockIdx.x * 4 + wave;
    if (d >= N) return;
    int row = rowptr[d], end = rowptr[d + 1];
    float adv = a_d[d];
    int g = lane >> 3, q = lane & 7;
    float acc[2][4] = {{0,0,0,0},{0,0,0,0}};
    float den = 0.f;
    for (int base = row; base < end; base += 64) {
        int cnt = min(64, end - base);
        float ev = 0.f; int sreg = 0;
        if (lane < cnt) {
            sreg = csr_src[base + lane];
            float v = a_s[sreg] + adv; v = (v > 0.f) ? v : NEG * v;
            ev = expf(v);
            den += ev;
        }
        int jmax = (cnt + 7) >> 3;
        for (int j = 0; j < jmax; j += 2) {
            int mA = 8 * j + g;                 // mA <= 55
            int mB = mA + 8;                    // mB <= 63 (jmax <= 8)
            int sA = __shfl(sreg, mA);
            int sB = __shfl(sreg, mB);
            float wA = __shfl(ev, mA);
            float wB = __shfl(ev, mB);
            const float* xpA = xh2 + (long)sA * F2 + q * 4;
            const float* xpB = xh2 + (long)sB * F2 + q * 4;
            float4 a0 = *(const float4*)(xpA);
            float4 a1 = *(const float4*)(xpA + 32);
            float4 b0 = *(const float4*)(xpB);
            float4 b1 = *(const float4*)(xpB + 32);
            acc[0][0] = fmaf(wA, a0.x, acc[0][0]); acc[0][1] = fmaf(wA, a0.y, acc[0][1]);
            acc[0][2] = fmaf(wA, a0.z, acc[0][2]); acc[0][3] = fmaf(wA, a0.w, acc[0][3]);
            acc[1][0] = fmaf(wA, a1.x, acc[1][0]); acc[1][1] = fmaf(wA, a1.y, acc[1][1]);
            acc[1][2] = fmaf(wA, a1.z, acc[1][2]); acc[1][3] = fmaf(wA, a1.w, acc[1][3]);
            acc[0][0] = fmaf(wB, b0.x, acc[0][0]); acc[0][1] = fmaf(wB, b0.y, acc[0][1]);
            acc[0][2] = fmaf(wB, b0.z, acc[0][2]); acc[0][3] = fmaf(wB, b0.w, acc[0][3]);
            acc[1][0] = fmaf(wB, b1.x, acc[1][0]); acc[1][1] = fmaf(wB, b1.y, acc[1][1]);
            acc[1][2] = fmaf(wB, b1.z, acc[1][2]); acc[1][3] = fmaf(wB, b1.w, acc[1][3]);
        }
    }
    #pragma unroll
    for (int o = 32; o > 0; o >>= 1) den += __shfl_xor(den, o);
    #pragma unroll
    for (int s0 = 0; s0 < 2; ++s0)
        #pragma unroll
        for (int p = 0; p < 4; ++p) {
            float v = acc[s0][p];
            v += __shfl_xor(v, 8);
            v += __shfl_xor(v, 16);
            v += __shfl_xor(v, 32);
            acc[s0][p] = v;
        }
    if (g == 0) {
        float inv = 1.0f / (den + 1e-16f);
        #pragma unroll
        for (int s0 = 0; s0 < 2; ++s0) {
            const float* bb = b2 + s0 * 32 + q * 4;
            float4 o4 = {acc[s0][0] * inv + bb[0], acc[s0][1] * inv + bb[1],
                         acc[s0][2] * inv + bb[2], acc[s0][3] * inv + bb[3]};
            *(float4*)(out2b + (long)d * F2 + s0 * 32 + q * 4) = o4;
        }
    }
}

// ------- decode via CSR: 8-lane groups, 2x-unrolled gather -------------------
__global__ __launch_bounds__(256) void decode_csr(
    const int* __restrict__ rowptr, const int* __restrict__ csr_src,
    const int* __restrict__ csr_eid, const float* __restrict__ z2b,
    float* __restrict__ out, int N)
{
    int wave = threadIdx.x >> 6, lane = threadIdx.x & 63;
    int d = blockIdx.x * 4 + wave;
    if (d >= N) return;
    int row = rowptr[d], end = rowptr[d + 1];
    int g = lane >> 3, q = lane & 7;
    const float* zd = z2b + (long)d * F2 + q * 4;
    float4 vd0 = *(const float4*)(zd);
    float4 vd1 = *(const float4*)(zd + 32);
    for (int base = row; base < end; base += 64) {
        int cnt = min(64, end - base);
        int sreg = 0, ereg = -1;
        if (lane < cnt) {
            sreg = csr_src[base + lane];
            ereg = csr_eid[base + lane];
        }
        int jmax = (cnt + 7) >> 3;
        for (int j = 0; j < jmax; j += 2) {
            int mA = 8 * j + g;
            int mB = mA + 8;                    // <= 63; overflow: eB=-1 -> skip
            int sA = __shfl(sreg, mA);
            int eA = __shfl(ereg, mA);
            int sB = __shfl(sreg, mB);
            int eB = __shfl(ereg, mB);
            const float* zsA = z2b + (long)sA * F2 + q * 4;
            const float* zsB = z2b + (long)sB * F2 + q * 4;
            float4 a0 = *(const float4*)(zsA);
            float4 a1 = *(const float4*)(zsA + 32);
            float4 b0 = *(const float4*)(zsB);
            float4 b1 = *(const float4*)(zsB + 32);
            float pA = vd0.x * a0.x + vd0.y * a0.y + vd0.z * a0.z + vd0.w * a0.w
                     + vd1.x * a1.x + vd1.y * a1.y + vd1.z * a1.z + vd1.w * a1.w;
            float pB = vd0.x * b0.x + vd0.y * b0.y + vd0.z * b0.z + vd0.w * b0.w
                     + vd1.x * b1.x + vd1.y * b1.y + vd1.z * b1.z + vd1.w * b1.w;
            pA += __shfl_xor(pA, 1);
            pB += __shfl_xor(pB, 1);
            pA += __shfl_xor(pA, 2);
            pB += __shfl_xor(pB, 2);
            pA += __shfl_xor(pA, 4);
            pB += __shfl_xor(pB, 4);
            if (q == 0 && eA >= 0) out[eA] = pA;
            if (q == 0 && eB >= 0) out[eB] = pB;
        }
    }
}

extern "C" void kernel_launch(void* const* d_in, const int* in_sizes, int n_in,
                              void* d_out, int out_size, void* d_ws, size_t ws_size,
                              hipStream_t stream) {
    const float* x   = (const float*)d_in[0];
    const int*   ei  = (const int*)d_in[1];
    const float* W1  = (const float*)d_in[2];
    const float* as1 = (const float*)d_in[3];
    const float* ad1 = (const float*)d_in[4];
    const float* b1  = (const float*)d_in[5];
    const float* W2  = (const float*)d_in[6];
    const float* as2 = (const float*)d_in[7];
    const float* ad2 = (const float*)d_in[8];
    const float* b2  = (const float*)d_in[9];

    int N  = in_sizes[0] / IN_F;   // 50000
    int E  = in_sizes[1] / 2;      // 600000
    int Ep = E + N;
    const int* ei_src = ei;
    const int* ei_dst = ei + E;

    float* ws = (float*)d_ws;
    size_t off = 0;
    auto alloc = [&](size_t n) { float* p = ws + off; off += (n + 63) & ~(size_t)63; return p; };

    _Float16* Gh   = (_Float16*)alloc((size_t)N * F1 / 2);
    _Float16* Gl   = (_Float16*)alloc((size_t)N * F1 / 2);
    _Float16* Wth  = (_Float16*)alloc(IN_F * F1 / 2);
    _Float16* Wtl  = (_Float16*)alloc(IN_F * F1 / 2);
    _Float16* W2th = (_Float16*)alloc(F1 * F2 / 2);
    _Float16* W2tl = (_Float16*)alloc(F1 * F2 / 2);
    float* xh2    = alloc((size_t)N * F2);
    float* out2b  = alloc((size_t)N * F2);
    float* a_src1 = alloc((size_t)N * H1);
    float* a_dst1 = alloc((size_t)N * H1);
    float* a_src2 = alloc(N);
    float* a_dst2 = alloc(N);
    float* UV4    = alloc(IN_F * 4);
    int* rowptr   = (int*)alloc(N + 64);
    int* rloc     = (int*)alloc(N + 64);
    int* csr_src  = (int*)alloc(Ep);
    int* csr_eid  = (int*)alloc(Ep);
    int* pos      = (int*)alloc(Ep);
    int* bsum     = (int*)alloc(64);
    int* deg      = (int*)alloc(N);
    hipMemsetAsync(deg, 0, (size_t)N * sizeof(int), stream);

    int NBLK = (N + 1023) / 1024;       // 49
    int NBH  = (Ep + 255) / 256;
    int NBS  = (Ep + 1023) / 1024;
    int NBA  = (N + 15) / 16;

    hist_uv_k<<<NBH + 40, 256, 0, stream>>>(ei_dst, deg, pos, E, Ep, NBH,
                                            W1, as1, ad1, UV4, Wth, Wtl,
                                            W2, W2th, W2tl);
    scanA_att_k<<<NBLK + NBA, 1024, 0, stream>>>(deg, rloc, bsum, N, NBLK,
                                                 x, UV4, a_src1, a_dst1);
    scat_fix_k<<<NBLK + NBS, 1024, 0, stream>>>(ei_src, ei_dst, rloc, bsum, pos,
                                                rowptr, csr_src, csr_eid,
                                                E, Ep, N, NBLK);

    // layer 1 aggregation
    agg1x<<<(N + 3) / 4, 256, 0, stream>>>(rowptr, csr_src, a_src1, a_dst1, x,
                                           Gh, Gl, N);
    // fused layer-1 GEMM + layer-2 GEMM (z stays in LDS)
    gemm12_fused<<<(N + 63) / 64, 256, 0, stream>>>(Gh, Gl, Wth, Wtl, b1,
                                                    W2th, W2tl, as2, ad2,
                                                    xh2, a_src2, a_dst2, N);
    agg2_csr<<<(N + 3) / 4, 256, 0, stream>>>(rowptr, csr_src, a_src2, a_dst2, xh2, b2, out2b, N);

    // decode
    decode_csr<<<(N + 3) / 4, 256, 0, stream>>>(rowptr, csr_src, csr_eid, out2b,
                                                (float*)d_out, N);
}

// Round 15
// 283.963 us; speedup vs baseline: 1.0833x; 1.0833x over previous
//
#include <hip/hip_runtime.h>
#include <math.h>

#define IN_F 128
#define F1 256   // H1*C1
#define H1 2
#define F2 64
#define NEG 0.2f

typedef _Float16 f16x8 __attribute__((ext_vector_type(8)));
typedef _Float16 f16x4 __attribute__((ext_vector_type(4)));
typedef float f32x4 __attribute__((ext_vector_type(4)));

// ------- fused layer-1 + layer-2 GEMM, v2 ----------------------------------
// R14 failure diagnosed: 128KB LDS -> 1 block/CU, 5 barriers -> latency-bound
// (MfmaUtil 8.6%). Fix: (1) z is WAVE-PRIVATE (each wave writes & reads only
// rows wave*16..+15) -> all barriers removed, early-return safe (N%16==0);
// (2) W fragments read fragment-ordered from GLOBAL (L2-hot, coalesced 16B)
// instead of LDS staging -> LDS = Zh+Zl = 64KB -> 2 blocks/CU, 8 waves/CU.
// Traffic win of fusion kept (z never touches HBM). Math bit-identical.
__global__ __launch_bounds__(256) void gemm12_fused(
    const _Float16* __restrict__ Gh, const _Float16* __restrict__ Gl,
    const _Float16* __restrict__ Wf1h, const _Float16* __restrict__ Wf1l,
    const float* __restrict__ b1,
    const _Float16* __restrict__ Wf2h, const _Float16* __restrict__ Wf2l,
    const float* __restrict__ as2, const float* __restrict__ ad2,
    float* __restrict__ xh2, float* __restrict__ a_src, float* __restrict__ a_dst,
    int N)
{
    __shared__ _Float16 Zh[64 * 256];        // 32 KB
    __shared__ _Float16 Zl[64 * 256];        // 32 KB

    int t = threadIdx.x;
    int wave = t >> 6, lane = t & 63;
    int quad = lane >> 4, l4 = lane & 15;
    int rt = blockIdx.x * 4 + wave;
    if (rt * 16 >= N) return;                // no barriers -> safe
    long mrow = (long)rt * 16 + l4;

    // ---- phases 1,2: layer-1 GEMM per head, z -> LDS (wave-private rows) ----
    #pragma unroll 1
    for (int h = 0; h < 2; ++h) {
        const _Float16* gh = Gh + mrow * F1 + h * 128 + quad * 8;
        const _Float16* gl = Gl + mrow * F1 + h * 128 + quad * 8;
        f16x8 ah[4], al[4];
        #pragma unroll
        for (int ks = 0; ks < 4; ++ks) {
            ah[ks] = *(const f16x8*)(gh + ks * 32);
            al[ks] = *(const f16x8*)(gl + ks * 32);
        }
        f32x4 acc[8];
        #pragma unroll
        for (int ct = 0; ct < 8; ++ct) acc[ct] = (f32x4){0.f, 0.f, 0.f, 0.f};
        #pragma unroll
        for (int ks = 0; ks < 4; ++ks) {
            #pragma unroll
            for (int ct = 0; ct < 8; ++ct) {
                int slot = h * 32 + ct * 4 + ks;
                f16x8 bh = *(const f16x8*)&Wf1h[((long)slot * 64 + lane) * 8];
                f16x8 bl = *(const f16x8*)&Wf1l[((long)slot * 64 + lane) * 8];
                acc[ct] = __builtin_amdgcn_mfma_f32_16x16x32_f16(ah[ks], bh, acc[ct], 0, 0, 0);
                acc[ct] = __builtin_amdgcn_mfma_f32_16x16x32_f16(al[ks], bh, acc[ct], 0, 0, 0);
                acc[ct] = __builtin_amdgcn_mfma_f32_16x16x32_f16(ah[ks], bl, acc[ct], 0, 0, 0);
            }
        }
        // epilogue: relu(acc+b1) -> split f16 -> LDS z (swizzled, own rows)
        #pragma unroll
        for (int ct = 0; ct < 8; ++ct) {
            int col = h * 128 + ct * 16 + l4;
            float b1c = b1[col];
            #pragma unroll
            for (int i = 0; i < 4; ++i) {
                int row = wave * 16 + quad * 4 + i;
                float v = fmaxf(acc[ct][i] + b1c, 0.f);
                _Float16 hi = (_Float16)v;
                int e = (row * 256 + col) ^ ((row & 7) << 3);
                Zh[e] = hi;
                Zl[e] = (_Float16)(v - (float)hi);
            }
        }
    }

    // ---- phase 3: layer-2 GEMM from LDS z + att2 epilogue -------------------
    {
        int row = wave * 16 + l4;            // own wave's rows only
        int swz = (row & 7) << 3;
        f16x8 ah[8], al[8];
        #pragma unroll
        for (int ks = 0; ks < 8; ++ks) {
            int e = (row * 256 + (quad * 8 + ks * 32)) ^ swz;
            ah[ks] = *(const f16x8*)&Zh[e];
            al[ks] = *(const f16x8*)&Zl[e];
        }
        f32x4 acc[4];
        #pragma unroll
        for (int ct = 0; ct < 4; ++ct) acc[ct] = (f32x4){0.f, 0.f, 0.f, 0.f};
        #pragma unroll
        for (int ks = 0; ks < 8; ++ks) {
            #pragma unroll
            for (int ct = 0; ct < 4; ++ct) {
                int slot = ct * 8 + ks;
                f16x8 bh = *(const f16x8*)&Wf2h[((long)slot * 64 + lane) * 8];
                f16x8 bl = *(const f16x8*)&Wf2l[((long)slot * 64 + lane) * 8];
                acc[ct] = __builtin_amdgcn_mfma_f32_16x16x32_f16(ah[ks], bh, acc[ct], 0, 0, 0);
                acc[ct] = __builtin_amdgcn_mfma_f32_16x16x32_f16(al[ks], bh, acc[ct], 0, 0, 0);
                acc[ct] = __builtin_amdgcn_mfma_f32_16x16x32_f16(ah[ks], bl, acc[ct], 0, 0, 0);
            }
        }
        int rbase = rt * 16 + quad * 4;
        float ps[4] = {0, 0, 0, 0}, pd[4] = {0, 0, 0, 0};
        #pragma unroll
        for (int ct = 0; ct < 4; ++ct) {
            int col = ct * 16 + l4;
            float asv = as2[col], adv = ad2[col];
            #pragma unroll
            for (int i = 0; i < 4; ++i) {
                xh2[(long)(rbase + i) * F2 + col] = acc[ct][i];
                ps[i] = fmaf(acc[ct][i], asv, ps[i]);
                pd[i] = fmaf(acc[ct][i], adv, pd[i]);
            }
        }
        #pragma unroll
        for (int o = 1; o < 16; o <<= 1) {
            #pragma unroll
            for (int i = 0; i < 4; ++i) {
                ps[i] += __shfl_xor(ps[i], o);
                pd[i] += __shfl_xor(pd[i], o);
            }
        }
        if (l4 == 0) {
            #pragma unroll
            for (int i = 0; i < 4; ++i) {
                a_src[rbase + i] = ps[i];
                a_dst[rbase + i] = pd[i];
            }
        }
    }
}

// ------- launch 1: histogram + PARALLEL UV prep + FRAGMENT-ORDERED W split ---
// W1/W2 split-f16 now written directly in MFMA fragment order:
// Wf1[(h*32+ct*4+ks)*64+lane]*8  holds f16(W1[(koff+j)*256 + h*128+col]),
// col=ct*16+(lane&15), koff=ks*32+(lane>>4)*8  (same values as before, new
// layout so gemm12_fused reads them coalesced from global/L2).
__global__ __launch_bounds__(256) void hist_uv_k(
    const int* __restrict__ ei_d, int* __restrict__ deg, int* __restrict__ pos,
    int E, int Ep, int NBH,
    const float* __restrict__ W1, const float* __restrict__ as1,
    const float* __restrict__ ad1, float* __restrict__ UV4,
    _Float16* __restrict__ Wf1h, _Float16* __restrict__ Wf1l,
    const float* __restrict__ W2,
    _Float16* __restrict__ Wf2h, _Float16* __restrict__ Wf2l)
{
    int b = (int)blockIdx.x;
    int t = threadIdx.x;
    if (b < NBH) {
        int i = b * 256 + t;
        if (i >= Ep) return;
        int d = (i < E) ? ei_d[i] : (i - E);
        pos[i] = atomicAdd(&deg[d], 1);
    } else if (b < NBH + 16) {
        // UV: pair p=(k,h), 16 lanes each, lane covers 8 contiguous c
        int p = (b - NBH) * 16 + (t >> 4);   // 0..255
        int l = t & 15;
        int k = p >> 1, h = p & 1;
        const float* wrow = W1 + (long)k * F1 + h * 128;
        const float* sa = as1 + h * 128;
        const float* da = ad1 + h * 128;
        int c0 = l * 8;
        float u = 0.f, v = 0.f;
        #pragma unroll
        for (int c = 0; c < 8; ++c) {
            float w = wrow[c0 + c];
            u = fmaf(w, sa[c0 + c], u);
            v = fmaf(w, da[c0 + c], v);
        }
        #pragma unroll
        for (int o = 1; o < 16; o <<= 1) {
            u += __shfl_xor(u, o);
            v += __shfl_xor(v, o);
        }
        if (l == 0) {
            UV4[k * 4 + h] = u;
            UV4[k * 4 + 2 + h] = v;
        }
    } else if (b < NBH + 32) {
        // W1 fragment-ordered split: gid -> n=gid/16 (0..255), kb=(gid%16)*8
        int gid = (b - NBH - 16) * 256 + t;
        int n = gid >> 4;
        int kb = (gid & 15) * 8;
        f16x8 hi, lo;
        #pragma unroll
        for (int c = 0; c < 8; ++c) {
            float w = W1[(long)(kb + c) * F1 + n];
            _Float16 hh = (_Float16)w;
            hi[c] = hh;
            lo[c] = (_Float16)(w - (float)hh);
        }
        int h = n >> 7, colh = n & 127;
        int ct = colh >> 4, l4c = colh & 15;
        int ks = kb >> 5, lq = (kb >> 3) & 3;
        int lanef = lq * 16 + l4c;
        int slot = h * 32 + ct * 4 + ks;
        *(f16x8*)&Wf1h[((long)slot * 64 + lanef) * 8] = hi;
        *(f16x8*)&Wf1l[((long)slot * 64 + lanef) * 8] = lo;
    } else {
        // W2 fragment-ordered split: gid -> n=gid/32 (0..63), kb=(gid%32)*8
        int gid = (b - NBH - 32) * 256 + t;
        int n = gid >> 5;
        int kb = (gid & 31) * 8;
        f16x8 hi, lo;
        #pragma unroll
        for (int c = 0; c < 8; ++c) {
            float w = W2[(long)(kb + c) * F2 + n];
            _Float16 hh = (_Float16)w;
            hi[c] = hh;
            lo[c] = (_Float16)(w - (float)hh);
        }
        int ct = n >> 4, l4c = n & 15;
        int ks = kb >> 5, lq = (kb >> 3) & 3;
        int lanef = lq * 16 + l4c;
        int slot = ct * 8 + ks;
        *(f16x8*)&Wf2h[((long)slot * 64 + lanef) * 8] = hi;
        *(f16x8*)&Wf2l[((long)slot * 64 + lanef) * 8] = lo;
    }
}

// ------- launch 2: per-block local scan -> rloc + att1v ----------------------
__global__ __launch_bounds__(1024) void scanA_att_k(
    const int* __restrict__ deg, int* __restrict__ rloc, int* __restrict__ bsum,
    int N, int NBLK,
    const float* __restrict__ x, const float* __restrict__ UV4,
    float* __restrict__ a_src, float* __restrict__ a_dst)
{
    if ((int)blockIdx.x < NBLK) {
        __shared__ int wsum[16];
        int t = threadIdx.x, lane = t & 63, w = t >> 6;
        int i = blockIdx.x * 1024 + t;
        int v = (i < N) ? deg[i] : 0;
        int incl = v;
        #pragma unroll
        for (int o = 1; o < 64; o <<= 1) {
            int nb = __shfl_up(incl, o);
            if (lane >= o) incl += nb;
        }
        if (lane == 63) wsum[w] = incl;
        __syncthreads();
        if (w == 0 && lane < 16) {
            int s = wsum[lane];
            #pragma unroll
            for (int o = 1; o < 16; o <<= 1) {
                int nb = __shfl_up(s, o);
                if (lane >= o) s += nb;
            }
            wsum[lane] = s;
        }
        __syncthreads();
        int woff = (w == 0) ? 0 : wsum[w - 1];
        if (i < N) rloc[i] = woff + incl - v;
        if (t == 1023) bsum[blockIdx.x] = woff + incl;
    } else {
        int wave = threadIdx.x >> 6, lane = threadIdx.x & 63;
        int n = ((int)blockIdx.x - NBLK) * 16 + wave;
        if (n >= N) return;
        float2 xv = ((const float2*)(x + (long)n * IN_F))[lane];
        float4 u0 = ((const float4*)UV4)[2 * lane];
        float4 u1 = ((const float4*)UV4)[2 * lane + 1];
        float p0 = xv.x * u0.x + xv.y * u1.x;
        float p1 = xv.x * u0.y + xv.y * u1.y;
        float p2 = xv.x * u0.z + xv.y * u1.z;
        float p3 = xv.x * u0.w + xv.y * u1.w;
        #pragma unroll
        for (int o = 32; o > 0; o >>= 1) {
            p0 += __shfl_xor(p0, o); p1 += __shfl_xor(p1, o);
            p2 += __shfl_xor(p2, o); p3 += __shfl_xor(p3, o);
        }
        if (lane == 0) {
            a_src[(long)n * 2 + 0] = p0; a_src[(long)n * 2 + 1] = p1;
            a_dst[(long)n * 2 + 0] = p2; a_dst[(long)n * 2 + 1] = p3;
        }
    }
}

// ------- launch 3 (fused): rowptr fixup + atomic-free scatter ----------------
__global__ __launch_bounds__(1024) void scat_fix_k(
    const int* __restrict__ ei_s, const int* __restrict__ ei_d,
    const int* __restrict__ rloc, const int* __restrict__ bsum,
    const int* __restrict__ pos, int* __restrict__ rowptr,
    int* __restrict__ csr_src, int* __restrict__ csr_eid,
    int E, int Ep, int N, int NBLK)
{
    __shared__ int bexs[64];
    __shared__ int tot_sh;
    int t = threadIdx.x;
    if (t < 64) {
        int v = (t < NBLK) ? bsum[t] : 0;
        int incl = v;
        #pragma unroll
        for (int o = 1; o < 64; o <<= 1) {
            int nb = __shfl_up(incl, o);
            if (t >= o) incl += nb;
        }
        bexs[t] = incl - v;
        if (t == NBLK - 1) tot_sh = incl;
    }
    __syncthreads();
    if ((int)blockIdx.x < NBLK) {
        int i = blockIdx.x * 1024 + t;
        if (i < N) rowptr[i] = rloc[i] + bexs[blockIdx.x];
        if ((int)blockIdx.x == NBLK - 1 && t == 0) rowptr[N] = tot_sh;
    } else {
        int i = ((int)blockIdx.x - NBLK) * 1024 + t;
        if (i >= Ep) return;
        int s = (i < E) ? ei_s[i] : (i - E);
        int d = (i < E) ? ei_d[i] : (i - E);
        int at = rloc[d] + bexs[d >> 10] + pos[i];
        csr_src[at] = s;
        csr_eid[at] = (i < E) ? i : -1;
    }
}

// ------- layer-1 aggregation: 16-lane groups, 2x-unrolled gather -------------
__global__ __launch_bounds__(256) void agg1x(
    const int* __restrict__ rowptr, const int* __restrict__ csr_src,
    const float* __restrict__ a_s, const float* __restrict__ a_d,  // [N,2]
    const float* __restrict__ x, _Float16* __restrict__ Gh,
    _Float16* __restrict__ Gl, int N)
{
    int wave = threadIdx.x >> 6, lane = threadIdx.x & 63;
    int d = blockIdx.x * 4 + wave;
    if (d >= N) return;
    int row = rowptr[d], end = rowptr[d + 1];
    int h = lane >> 5, l5 = lane & 31;
    int g = lane >> 4, q = lane & 15;
    float adh = a_d[(long)d * 2 + h];
    // acc[seg][head][4]: seg0=ch q*4, seg1=ch 64+q*4
    float acc[2][2][4];
    #pragma unroll
    for (int s0 = 0; s0 < 2; ++s0)
        #pragma unroll
        for (int h0 = 0; h0 < 2; ++h0)
            #pragma unroll
            for (int p = 0; p < 4; ++p) acc[s0][h0][p] = 0.f;
    float den = 0.f;
    for (int base = row; base < end; base += 32) {
        int cnt = min(32, end - base);
        int sreg = 0; float e = 0.f;
        if (l5 < cnt) {
            sreg = csr_src[base + l5];
            float v = a_s[(long)sreg * 2 + h] + adh;
            v = (v > 0.f) ? v : NEG * v;
            e = expf(v);
            den += e;
        }
        int jmax = (cnt + 3) >> 2;
        for (int j = 0; j < jmax; j += 2) {
            int mA = 4 * j + g;                 // mA <= 27
            int mB = mA + 4;                    // mB <= 31 (jmax <= 8)
            int sA = __shfl(sreg, mA);
            int sB = __shfl(sreg, mB);
            float w0A = __shfl(e, mA);
            float w1A = __shfl(e, 32 | mA);
            float w0B = __shfl(e, mB);
            float w1B = __shfl(e, 32 | mB);
            const float* xpA = x + (long)sA * IN_F + q * 4;
            const float* xpB = x + (long)sB * IN_F + q * 4;
            float4 a0 = *(const float4*)(xpA);
            float4 a1 = *(const float4*)(xpA + 64);
            float4 b0 = *(const float4*)(xpB);
            float4 b1 = *(const float4*)(xpB + 64);
            acc[0][0][0] = fmaf(w0A, a0.x, acc[0][0][0]);
            acc[0][0][1] = fmaf(w0A, a0.y, acc[0][0][1]);
            acc[0][0][2] = fmaf(w0A, a0.z, acc[0][0][2]);
            acc[0][0][3] = fmaf(w0A, a0.w, acc[0][0][3]);
            acc[1][0][0] = fmaf(w0A, a1.x, acc[1][0][0]);
            acc[1][0][1] = fmaf(w0A, a1.y, acc[1][0][1]);
            acc[1][0][2] = fmaf(w0A, a1.z, acc[1][0][2]);
            acc[1][0][3] = fmaf(w0A, a1.w, acc[1][0][3]);
            acc[0][1][0] = fmaf(w1A, a0.x, acc[0][1][0]);
            acc[0][1][1] = fmaf(w1A, a0.y, acc[0][1][1]);
            acc[0][1][2] = fmaf(w1A, a0.z, acc[0][1][2]);
            acc[0][1][3] = fmaf(w1A, a0.w, acc[0][1][3]);
            acc[1][1][0] = fmaf(w1A, a1.x, acc[1][1][0]);
            acc[1][1][1] = fmaf(w1A, a1.y, acc[1][1][1]);
            acc[1][1][2] = fmaf(w1A, a1.z, acc[1][1][2]);
            acc[1][1][3] = fmaf(w1A, a1.w, acc[1][1][3]);
            acc[0][0][0] = fmaf(w0B, b0.x, acc[0][0][0]);
            acc[0][0][1] = fmaf(w0B, b0.y, acc[0][0][1]);
            acc[0][0][2] = fmaf(w0B, b0.z, acc[0][0][2]);
            acc[0][0][3] = fmaf(w0B, b0.w, acc[0][0][3]);
            acc[1][0][0] = fmaf(w0B, b1.x, acc[1][0][0]);
            acc[1][0][1] = fmaf(w0B, b1.y, acc[1][0][1]);
            acc[1][0][2] = fmaf(w0B, b1.z, acc[1][0][2]);
            acc[1][0][3] = fmaf(w0B, b1.w, acc[1][0][3]);
            acc[0][1][0] = fmaf(w1B, b0.x, acc[0][1][0]);
            acc[0][1][1] = fmaf(w1B, b0.y, acc[0][1][1]);
            acc[0][1][2] = fmaf(w1B, b0.z, acc[0][1][2]);
            acc[0][1][3] = fmaf(w1B, b0.w, acc[0][1][3]);
            acc[1][1][0] = fmaf(w1B, b1.x, acc[1][1][0]);
            acc[1][1][1] = fmaf(w1B, b1.y, acc[1][1][1]);
            acc[1][1][2] = fmaf(w1B, b1.z, acc[1][1][2]);
            acc[1][1][3] = fmaf(w1B, b1.w, acc[1][1][3]);
        }
    }
    // den: reduce within each 32-lane half, then exchange across halves
    #pragma unroll
    for (int o = 16; o > 0; o >>= 1) den += __shfl_xor(den, o);
    float den_o = __shfl_xor(den, 32);
    float den0 = (h == 0) ? den : den_o;
    float den1 = (h == 0) ? den_o : den;
    // cross-group combine
    #pragma unroll
    for (int s0 = 0; s0 < 2; ++s0)
        #pragma unroll
        for (int h0 = 0; h0 < 2; ++h0)
            #pragma unroll
            for (int p = 0; p < 4; ++p) {
                float v = acc[s0][h0][p];
                v += __shfl_xor(v, 16);
                v += __shfl_xor(v, 32);
                acc[s0][h0][p] = v;
            }
    if (g == 0) {
        float inv0 = 1.0f / (den0 + 1e-16f);
        float inv1 = 1.0f / (den1 + 1e-16f);
        #pragma unroll
        for (int h0 = 0; h0 < 2; ++h0) {
            float inv = (h0 == 0) ? inv0 : inv1;
            #pragma unroll
            for (int s0 = 0; s0 < 2; ++s0) {
                f16x4 hi, lo;
                #pragma unroll
                for (int p = 0; p < 4; ++p) {
                    float v = acc[s0][h0][p] * inv;
                    hi[p] = (_Float16)v;
                    lo[p] = (_Float16)(v - (float)hi[p]);
                }
                long base = (long)d * F1 + h0 * 128 + s0 * 64 + q * 4;
                *(f16x4*)(Gh + base) = hi;
                *(f16x4*)(Gl + base) = lo;
            }
        }
    }
}

// ------- layer-2 aggregation: 8-lane groups, 2x-unrolled gather --------------
__global__ __launch_bounds__(256) void agg2_csr(
    const int* __restrict__ rowptr, const int* __restrict__ csr_src,
    const float* __restrict__ a_s, const float* __restrict__ a_d,  // [N]
    const float* __restrict__ xh2, const float* __restrict__ b2,
    float* __restrict__ out2b, int N)
{
    int wave = threadIdx.x >> 6, lane = threadIdx.x & 63;
    int d = blockIdx.x * 4 + wave;
    if (d >= N) return;
    int row = rowptr[d], end = rowptr[d + 1];
    float adv = a_d[d];
    int g = lane >> 3, q = lane & 7;
    float acc[2][4] = {{0,0,0,0},{0,0,0,0}};
    float den = 0.f;
    for (int base = row; base < end; base += 64) {
        int cnt = min(64, end - base);
        float ev = 0.f; int sreg = 0;
        if (lane < cnt) {
            sreg = csr_src[base + lane];
            float v = a_s[sreg] + adv; v = (v > 0.f) ? v : NEG * v;
            ev = expf(v);
            den += ev;
        }
        int jmax = (cnt + 7) >> 3;
        for (int j = 0; j < jmax; j += 2) {
            int mA = 8 * j + g;                 // mA <= 55
            int mB = mA + 8;                    // mB <= 63 (jmax <= 8)
            int sA = __shfl(sreg, mA);
            int sB = __shfl(sreg, mB);
            float wA = __shfl(ev, mA);
            float wB = __shfl(ev, mB);
            const float* xpA = xh2 + (long)sA * F2 + q * 4;
            const float* xpB = xh2 + (long)sB * F2 + q * 4;
            float4 a0 = *(const float4*)(xpA);
            float4 a1 = *(const float4*)(xpA + 32);
            float4 b0 = *(const float4*)(xpB);
            float4 b1 = *(const float4*)(xpB + 32);
            acc[0][0] = fmaf(wA, a0.x, acc[0][0]); acc[0][1] = fmaf(wA, a0.y, acc[0][1]);
            acc[0][2] = fmaf(wA, a0.z, acc[0][2]); acc[0][3] = fmaf(wA, a0.w, acc[0][3]);
            acc[1][0] = fmaf(wA, a1.x, acc[1][0]); acc[1][1] = fmaf(wA, a1.y, acc[1][1]);
            acc[1][2] = fmaf(wA, a1.z, acc[1][2]); acc[1][3] = fmaf(wA, a1.w, acc[1][3]);
            acc[0][0] = fmaf(wB, b0.x, acc[0][0]); acc[0][1] = fmaf(wB, b0.y, acc[0][1]);
            acc[0][2] = fmaf(wB, b0.z, acc[0][2]); acc[0][3] = fmaf(wB, b0.w, acc[0][3]);
            acc[1][0] = fmaf(wB, b1.x, acc[1][0]); acc[1][1] = fmaf(wB, b1.y, acc[1][1]);
            acc[1][2] = fmaf(wB, b1.z, acc[1][2]); acc[1][3] = fmaf(wB, b1.w, acc[1][3]);
        }
    }
    #pragma unroll
    for (int o = 32; o > 0; o >>= 1) den += __shfl_xor(den, o);
    #pragma unroll
    for (int s0 = 0; s0 < 2; ++s0)
        #pragma unroll
        for (int p = 0; p < 4; ++p) {
            float v = acc[s0][p];
            v += __shfl_xor(v, 8);
            v += __shfl_xor(v, 16);
            v += __shfl_xor(v, 32);
            acc[s0][p] = v;
        }
    if (g == 0) {
        float inv = 1.0f / (den + 1e-16f);
        #pragma unroll
        for (int s0 = 0; s0 < 2; ++s0) {
            const float* bb = b2 + s0 * 32 + q * 4;
            float4 o4 = {acc[s0][0] * inv + bb[0], acc[s0][1] * inv + bb[1],
                         acc[s0][2] * inv + bb[2], acc[s0][3] * inv + bb[3]};
            *(float4*)(out2b + (long)d * F2 + s0 * 32 + q * 4) = o4;
        }
    }
}

// ------- decode via CSR: 8-lane groups, 2x-unrolled gather -------------------
__global__ __launch_bounds__(256) void decode_csr(
    const int* __restrict__ rowptr, const int* __restrict__ csr_src,
    const int* __restrict__ csr_eid, const float* __restrict__ z2b,
    float* __restrict__ out, int N)
{
    int wave = threadIdx.x >> 6, lane = threadIdx.x & 63;
    int d = blockIdx.x * 4 + wave;
    if (d >= N) return;
    int row = rowptr[d], end = rowptr[d + 1];
    int g = lane >> 3, q = lane & 7;
    const float* zd = z2b + (long)d * F2 + q * 4;
    float4 vd0 = *(const float4*)(zd);
    float4 vd1 = *(const float4*)(zd + 32);
    for (int base = row; base < end; base += 64) {
        int cnt = min(64, end - base);
        int sreg = 0, ereg = -1;
        if (lane < cnt) {
            sreg = csr_src[base + lane];
            ereg = csr_eid[base + lane];
        }
        int jmax = (cnt + 7) >> 3;
        for (int j = 0; j < jmax; j += 2) {
            int mA = 8 * j + g;
            int mB = mA + 8;                    // <= 63; overflow: eB=-1 -> skip
            int sA = __shfl(sreg, mA);
            int eA = __shfl(ereg, mA);
            int sB = __shfl(sreg, mB);
            int eB = __shfl(ereg, mB);
            const float* zsA = z2b + (long)sA * F2 + q * 4;
            const float* zsB = z2b + (long)sB * F2 + q * 4;
            float4 a0 = *(const float4*)(zsA);
            float4 a1 = *(const float4*)(zsA + 32);
            float4 b0 = *(const float4*)(zsB);
            float4 b1 = *(const float4*)(zsB + 32);
            float pA = vd0.x * a0.x + vd0.y * a0.y + vd0.z * a0.z + vd0.w * a0.w
                     + vd1.x * a1.x + vd1.y * a1.y + vd1.z * a1.z + vd1.w * a1.w;
            float pB = vd0.x * b0.x + vd0.y * b0.y + vd0.z * b0.z + vd0.w * b0.w
                     + vd1.x * b1.x + vd1.y * b1.y + vd1.z * b1.z + vd1.w * b1.w;
            pA += __shfl_xor(pA, 1);
            pB += __shfl_xor(pB, 1);
            pA += __shfl_xor(pA, 2);
            pB += __shfl_xor(pB, 2);
            pA += __shfl_xor(pA, 4);
            pB += __shfl_xor(pB, 4);
            if (q == 0 && eA >= 0) out[eA] = pA;
            if (q == 0 && eB >= 0) out[eB] = pB;
        }
    }
}

extern "C" void kernel_launch(void* const* d_in, const int* in_sizes, int n_in,
                              void* d_out, int out_size, void* d_ws, size_t ws_size,
                              hipStream_t stream) {
    const float* x   = (const float*)d_in[0];
    const int*   ei  = (const int*)d_in[1];
    const float* W1  = (const float*)d_in[2];
    const float* as1 = (const float*)d_in[3];
    const float* ad1 = (const float*)d_in[4];
    const float* b1  = (const float*)d_in[5];
    const float* W2  = (const float*)d_in[6];
    const float* as2 = (const float*)d_in[7];
    const float* ad2 = (const float*)d_in[8];
    const float* b2  = (const float*)d_in[9];

    int N  = in_sizes[0] / IN_F;   // 50000
    int E  = in_sizes[1] / 2;      // 600000
    int Ep = E + N;
    const int* ei_src = ei;
    const int* ei_dst = ei + E;

    float* ws = (float*)d_ws;
    size_t off = 0;
    auto alloc = [&](size_t n) { float* p = ws + off; off += (n + 63) & ~(size_t)63; return p; };

    _Float16* Gh   = (_Float16*)alloc((size_t)N * F1 / 2);
    _Float16* Gl   = (_Float16*)alloc((size_t)N * F1 / 2);
    _Float16* Wf1h = (_Float16*)alloc(IN_F * F1 / 2);
    _Float16* Wf1l = (_Float16*)alloc(IN_F * F1 / 2);
    _Float16* Wf2h = (_Float16*)alloc(F1 * F2 / 2);
    _Float16* Wf2l = (_Float16*)alloc(F1 * F2 / 2);
    float* xh2    = alloc((size_t)N * F2);
    float* out2b  = alloc((size_t)N * F2);
    float* a_src1 = alloc((size_t)N * H1);
    float* a_dst1 = alloc((size_t)N * H1);
    float* a_src2 = alloc(N);
    float* a_dst2 = alloc(N);
    float* UV4    = alloc(IN_F * 4);
    int* rowptr   = (int*)alloc(N + 64);
    int* rloc     = (int*)alloc(N + 64);
    int* csr_src  = (int*)alloc(Ep);
    int* csr_eid  = (int*)alloc(Ep);
    int* pos      = (int*)alloc(Ep);
    int* bsum     = (int*)alloc(64);
    int* deg      = (int*)alloc(N);
    hipMemsetAsync(deg, 0, (size_t)N * sizeof(int), stream);

    int NBLK = (N + 1023) / 1024;       // 49
    int NBH  = (Ep + 255) / 256;
    int NBS  = (Ep + 1023) / 1024;
    int NBA  = (N + 15) / 16;

    hist_uv_k<<<NBH + 40, 256, 0, stream>>>(ei_dst, deg, pos, E, Ep, NBH,
                                            W1, as1, ad1, UV4, Wf1h, Wf1l,
                                            W2, Wf2h, Wf2l);
    scanA_att_k<<<NBLK + NBA, 1024, 0, stream>>>(deg, rloc, bsum, N, NBLK,
                                                 x, UV4, a_src1, a_dst1);
    scat_fix_k<<<NBLK + NBS, 1024, 0, stream>>>(ei_src, ei_dst, rloc, bsum, pos,
                                                rowptr, csr_src, csr_eid,
                                                E, Ep, N, NBLK);

    // layer 1 aggregation
    agg1x<<<(N + 3) / 4, 256, 0, stream>>>(rowptr, csr_src, a_src1, a_dst1, x,
                                           Gh, Gl, N);
    // fused layer-1 GEMM + layer-2 GEMM (z in wave-private LDS, no barriers)
    gemm12_fused<<<(N + 63) / 64, 256, 0, stream>>>(Gh, Gl, Wf1h, Wf1l, b1,
                                                    Wf2h, Wf2l, as2, ad2,
                                                    xh2, a_src2, a_dst2, N);
    agg2_csr<<<(N + 3) / 4, 256, 0, stream>>>(rowptr, csr_src, a_src2, a_dst2, xh2, b2, out2b, N);

    // decode
    decode_csr<<<(N + 3) / 4, 256, 0, stream>>>(rowptr, csr_src, csr_eid, out2b,
                                                (float*)d_out, N);
}